// Round 3
// baseline (246.965 us; speedup 1.0000x reference)
//
#include <hip/hip_runtime.h>
#include <math.h>

#define TT 2048
#define HH 128
#define ROWS 4
#define SP 132  // LDS row stride (floats), padded

__device__ __forceinline__ float dot4(float4 a, float4 b) {
    return a.x * b.x + a.y * b.y + a.z * b.z + a.w * b.w;
}

// ---- fused v,q,k,o projections + f/i gates, from LDS activation rows ----
// Mapping: h = tid&127 (output unit), rg = tid>>7 (row pair rg*2, rg*2+1).
// Each thread: 4 weight streams (one row per matrix), 8 accumulators.
__device__ __forceinline__ void proj_block(int t0, const float* __restrict__ xls,
        const float* __restrict__ w_v, const float* __restrict__ b_v,
        const float* __restrict__ w_q, const float* __restrict__ b_q,
        const float* __restrict__ w_k, const float* __restrict__ b_k,
        const float* __restrict__ w_o, const float* __restrict__ b_o,
        float* __restrict__ vb, float* __restrict__ qb,
        float* __restrict__ kb, float* __restrict__ ob) {
    int tid = threadIdx.x;
    int h = tid & 127, rg = tid >> 7;
    const float* x0 = xls + (rg * 2) * SP;
    const float* x1 = xls + (rg * 2 + 1) * SP;
    const float* wvr = w_v + h * HH;
    const float* wqr = w_q + h * HH;
    const float* wkr = w_k + h * HH;
    const float* wor = w_o + h * HH;
    float av0 = 0, av1 = 0, aq0 = 0, aq1 = 0, ak0 = 0, ak1 = 0, ao0 = 0, ao1 = 0;
#pragma unroll 8
    for (int c = 0; c < HH; c += 4) {
        float4 xa = *(const float4*)(x0 + c);
        float4 xb = *(const float4*)(x1 + c);
        float4 wv4 = *(const float4*)(wvr + c);
        float4 wq4 = *(const float4*)(wqr + c);
        float4 wk4 = *(const float4*)(wkr + c);
        float4 wo4 = *(const float4*)(wor + c);
        av0 += dot4(xa, wv4); av1 += dot4(xb, wv4);
        aq0 += dot4(xa, wq4); aq1 += dot4(xb, wq4);
        ak0 += dot4(xa, wk4); ak1 += dot4(xb, wk4);
        ao0 += dot4(xa, wo4); ao1 += dot4(xb, wo4);
    }
    const float ks = 0.088388347648318447f;  // 1/sqrt(128)
    float bv = b_v[h], bq = b_q[h], bk = b_k[h], bo = b_o[h];
    int ta = t0 + rg * 2, tb = ta + 1;
    vb[ta * HH + h] = av0 + bv;          vb[tb * HH + h] = av1 + bv;
    qb[ta * HH + h] = aq0 + bq;          qb[tb * HH + h] = aq1 + bq;
    kb[ta * HH + h] = ak0 * ks + bk;     kb[tb * HH + h] = ak1 * ks + bk;
    ob[ta * HH + h] = 1.f / (1.f + expf(-(ao0 + bo)));
    ob[tb * HH + h] = 1.f / (1.f + expf(-(ao1 + bo)));
}

// f/i scalar gates: wave wv handles row wv. Call AFTER xls rows are visible.
__device__ __forceinline__ void proj_fi(int t0, const float* __restrict__ xls,
        const float* __restrict__ w_f, const float* __restrict__ b_f,
        const float* __restrict__ w_i, const float* __restrict__ b_i,
        const int* __restrict__ start, float* __restrict__ g, float* __restrict__ iexp) {
    int tid = threadIdx.x;
    int wv = tid >> 6, lane = tid & 63;
    const float* x = xls + wv * SP + 2 * lane;
    float pf = x[0] * w_f[2 * lane] + x[1] * w_f[2 * lane + 1];
    float pi = x[0] * w_i[2 * lane] + x[1] * w_i[2 * lane + 1];
#pragma unroll
    for (int off = 1; off <= 32; off <<= 1) {
        pf += __shfl_xor(pf, off, 64);
        pi += __shfl_xor(pi, off, 64);
    }
    if (lane == 0) {
        int t = t0 + wv;
        g[t] = start[t] ? 0.f : 1.f / (1.f + expf(-(pf + b_f[0])));
        iexp[t] = expf(pi + b_i[0]);
    }
}

// mLSTM attention: wave wv owns row t0+wv; lane covers dims {2l, 2l+1}.
// Writes h row into hs (wave-local).
__device__ __forceinline__ void attn_row(int t0,
        const float* __restrict__ kb, const float* __restrict__ vb,
        const float* __restrict__ qb, const float* __restrict__ ob,
        const float* __restrict__ g, const float* __restrict__ iexp,
        const int* __restrict__ start, float* __restrict__ hs) {
    int tid = threadIdx.x;
    int wv = tid >> 6, lane = tid & 63;
    int t = t0 + wv;
    float2 q2 = *(const float2*)(qb + t * HH + 2 * lane);
    float nx = 0.f, ny = 0.f, dsum = 0.f, decay = 1.f;
    int tp = t;
    while (true) {
        float2 k2 = *(const float2*)(kb + tp * HH + 2 * lane);
        float p = k2.x * q2.x + k2.y * q2.y;
#pragma unroll
        for (int off = 1; off <= 32; off <<= 1) p += __shfl_xor(p, off, 64);
        float coeff = decay * iexp[tp] * p;
        float2 v2 = *(const float2*)(vb + tp * HH + 2 * lane);
        nx += coeff * v2.x; ny += coeff * v2.y;
        dsum += coeff;
        if (tp == 0 || start[tp]) break;
        decay *= g[tp];
        tp--;
    }
    float inv = 1.f / fmaxf(fabsf(dsum), 1.f);
    float2 o2 = *(const float2*)(ob + t * HH + 2 * lane);
    float2 h2;
    h2.x = o2.x * nx * inv;
    h2.y = o2.y * ny * inv;
    *(float2*)(hs + wv * SP + 2 * lane) = h2;
}

// ---------------- K1: e = emb @ w_in.T + b_in; layer-0 projections ----------------
__global__ __launch_bounds__(256, 2) void k1_kernel(
        const float* __restrict__ emb, const int* __restrict__ start,
        const float* __restrict__ w_in, const float* __restrict__ b_in,
        const float* __restrict__ w_v, const float* __restrict__ b_v,
        const float* __restrict__ w_q, const float* __restrict__ b_q,
        const float* __restrict__ w_k, const float* __restrict__ b_k,
        const float* __restrict__ w_o, const float* __restrict__ b_o,
        const float* __restrict__ w_f, const float* __restrict__ b_f,
        const float* __restrict__ w_i, const float* __restrict__ b_i,
        float* __restrict__ e, float* __restrict__ kb, float* __restrict__ vb,
        float* __restrict__ qb, float* __restrict__ ob,
        float* __restrict__ g, float* __restrict__ iexp) {
    __shared__ float xs[ROWS * SP];
    __shared__ float es[ROWS * SP];
    int tid = threadIdx.x;
    int t0 = blockIdx.x * ROWS;
    int wv = tid >> 6, lane = tid & 63;
    // stage emb: wave wv loads row wv
    *(float2*)(xs + wv * SP + 2 * lane) = *(const float2*)(emb + (t0 + wv) * HH + 2 * lane);
    __syncthreads();
    int h = tid & 127, rg = tid >> 7;
    const float* x0 = xs + (rg * 2) * SP;
    const float* x1 = xs + (rg * 2 + 1) * SP;
    const float* wr = w_in + h * HH;
    float a0 = 0, a1 = 0;
#pragma unroll 8
    for (int c = 0; c < HH; c += 4) {
        float4 w4 = *(const float4*)(wr + c);
        a0 += dot4(*(const float4*)(x0 + c), w4);
        a1 += dot4(*(const float4*)(x1 + c), w4);
    }
    float bh = b_in[h];
    a0 += bh; a1 += bh;
    int ta = t0 + rg * 2, tb = ta + 1;
    e[ta * HH + h] = a0; e[tb * HH + h] = a1;
    es[(rg * 2) * SP + h] = a0; es[(rg * 2 + 1) * SP + h] = a1;
    __syncthreads();
    proj_block(t0, es, w_v, b_v, w_q, b_q, w_k, b_k, w_o, b_o, vb, qb, kb, ob);
    proj_fi(t0, es, w_f, b_f, w_i, b_i, start, g, iexp);
}

// ---------------- K2: attn0 + ff0 + layer-1 projections ----------------
__global__ __launch_bounds__(256, 2) void k2_kernel(
        const int* __restrict__ start, const float* __restrict__ e,
        const float* __restrict__ k0, const float* __restrict__ v0,
        const float* __restrict__ q0, const float* __restrict__ o0,
        const float* __restrict__ g0, const float* __restrict__ i0,
        const float* __restrict__ w_ff, const float* __restrict__ b_ff,
        const float* __restrict__ w_v, const float* __restrict__ b_v,
        const float* __restrict__ w_q, const float* __restrict__ b_q,
        const float* __restrict__ w_k, const float* __restrict__ b_k,
        const float* __restrict__ w_o, const float* __restrict__ b_o,
        const float* __restrict__ w_f, const float* __restrict__ b_f,
        const float* __restrict__ w_i, const float* __restrict__ b_i,
        float* __restrict__ kb, float* __restrict__ vb,
        float* __restrict__ qb, float* __restrict__ ob,
        float* __restrict__ g, float* __restrict__ iexp) {
    __shared__ float es[ROWS * SP];
    __shared__ float hs[ROWS * SP];
    __shared__ float zs[ROWS * SP];
    int tid = threadIdx.x;
    int t0 = blockIdx.x * ROWS;
    int wv = tid >> 6, lane = tid & 63;
    // issue e stage load; value lands after attention (overlap)
    float2 ev = *(const float2*)(e + (t0 + wv) * HH + 2 * lane);
    attn_row(t0, k0, v0, q0, o0, g0, i0, start, hs);
    *(float2*)(es + wv * SP + 2 * lane) = ev;
    __syncthreads();
    // ff: z = lrelu([h, e] @ w_ff.T + b_ff), 2 rows per thread
    int h = tid & 127, rg = tid >> 7;
    const float* h0p = hs + (rg * 2) * SP;
    const float* h1p = hs + (rg * 2 + 1) * SP;
    const float* e0p = es + (rg * 2) * SP;
    const float* e1p = es + (rg * 2 + 1) * SP;
    const float* wfr = w_ff + h * 256;
    float a0 = 0, a1 = 0;
#pragma unroll 8
    for (int c = 0; c < HH; c += 4) {
        float4 wA = *(const float4*)(wfr + c);
        float4 wB = *(const float4*)(wfr + 128 + c);
        a0 += dot4(*(const float4*)(h0p + c), wA);
        a1 += dot4(*(const float4*)(h1p + c), wA);
        a0 += dot4(*(const float4*)(e0p + c), wB);
        a1 += dot4(*(const float4*)(e1p + c), wB);
    }
    float bh = b_ff[h];
    a0 += bh; a1 += bh;
    a0 = a0 > 0.f ? a0 : 0.01f * a0;
    a1 = a1 > 0.f ? a1 : 0.01f * a1;
    zs[(rg * 2) * SP + h] = a0;
    zs[(rg * 2 + 1) * SP + h] = a1;
    __syncthreads();
    proj_block(t0, zs, w_v, b_v, w_q, b_q, w_k, b_k, w_o, b_o, vb, qb, kb, ob);
    proj_fi(t0, zs, w_f, b_f, w_i, b_i, start, g, iexp);
}

// ---------------- K3: attn1 + ff1 + final dense ----------------
__global__ __launch_bounds__(256, 2) void k3_kernel(
        const int* __restrict__ start, const float* __restrict__ e,
        const float* __restrict__ k1, const float* __restrict__ v1,
        const float* __restrict__ q1, const float* __restrict__ o1,
        const float* __restrict__ g1, const float* __restrict__ i1,
        const float* __restrict__ w_ff, const float* __restrict__ b_ff,
        const float* __restrict__ w_out, const float* __restrict__ b_out,
        float* __restrict__ out) {
    __shared__ float es[ROWS * SP];
    __shared__ float hs[ROWS * SP];
    __shared__ float zs[ROWS * SP];
    int tid = threadIdx.x;
    int t0 = blockIdx.x * ROWS;
    int wv = tid >> 6, lane = tid & 63;
    float2 ev = *(const float2*)(e + (t0 + wv) * HH + 2 * lane);
    attn_row(t0, k1, v1, q1, o1, g1, i1, start, hs);
    *(float2*)(es + wv * SP + 2 * lane) = ev;
    __syncthreads();
    int h = tid & 127, rg = tid >> 7;
    const float* h0p = hs + (rg * 2) * SP;
    const float* h1p = hs + (rg * 2 + 1) * SP;
    const float* e0p = es + (rg * 2) * SP;
    const float* e1p = es + (rg * 2 + 1) * SP;
    const float* wfr = w_ff + h * 256;
    float a0 = 0, a1 = 0;
#pragma unroll 8
    for (int c = 0; c < HH; c += 4) {
        float4 wA = *(const float4*)(wfr + c);
        float4 wB = *(const float4*)(wfr + 128 + c);
        a0 += dot4(*(const float4*)(h0p + c), wA);
        a1 += dot4(*(const float4*)(h1p + c), wA);
        a0 += dot4(*(const float4*)(e0p + c), wB);
        a1 += dot4(*(const float4*)(e1p + c), wB);
    }
    float bh = b_ff[h];
    a0 += bh; a1 += bh;
    a0 = a0 > 0.f ? a0 : 0.01f * a0;
    a1 = a1 > 0.f ? a1 : 0.01f * a1;
    zs[(rg * 2) * SP + h] = a0;
    zs[(rg * 2 + 1) * SP + h] = a1;
    __syncthreads();
    const float* z0p = zs + (rg * 2) * SP;
    const float* z1p = zs + (rg * 2 + 1) * SP;
    const float* wor = w_out + h * HH;
    float o0a = 0, o1a = 0;
#pragma unroll 8
    for (int c = 0; c < HH; c += 4) {
        float4 w4 = *(const float4*)(wor + c);
        o0a += dot4(*(const float4*)(z0p + c), w4);
        o1a += dot4(*(const float4*)(z1p + c), w4);
    }
    float bo = b_out[h];
    int ta = t0 + rg * 2, tb = ta + 1;
    out[ta * HH + h] = o0a + bo;
    out[tb * HH + h] = o1a + bo;
}

extern "C" void kernel_launch(void* const* d_in, const int* in_sizes, int n_in,
                              void* d_out, int out_size, void* d_ws, size_t ws_size,
                              hipStream_t stream) {
    const float* emb   = (const float*)d_in[0];
    const int*   start = (const int*)  d_in[1];
    const float* w_in  = (const float*)d_in[2];
    const float* b_in  = (const float*)d_in[3];
    const float* w_out = (const float*)d_in[4];
    const float* b_out = (const float*)d_in[5];
    const float* w_f   = (const float*)d_in[6];
    const float* b_f   = (const float*)d_in[7];
    const float* w_i   = (const float*)d_in[8];
    const float* b_i   = (const float*)d_in[9];
    const float* w_v   = (const float*)d_in[10];
    const float* b_v   = (const float*)d_in[11];
    const float* w_q   = (const float*)d_in[12];
    const float* b_q   = (const float*)d_in[13];
    const float* w_k   = (const float*)d_in[14];
    const float* b_k   = (const float*)d_in[15];
    const float* w_o   = (const float*)d_in[16];
    const float* b_o   = (const float*)d_in[17];
    const float* w_ff  = (const float*)d_in[18];
    const float* b_ff  = (const float*)d_in[19];
    float* out = (float*)d_out;

    float* ws = (float*)d_ws;
    float* e   = ws; ws += TT * HH;
    float* k0b = ws; ws += TT * HH;
    float* v0b = ws; ws += TT * HH;
    float* q0b = ws; ws += TT * HH;
    float* o0b = ws; ws += TT * HH;
    float* k1b = ws; ws += TT * HH;
    float* v1b = ws; ws += TT * HH;
    float* q1b = ws; ws += TT * HH;
    float* o1b = ws; ws += TT * HH;
    float* g0  = ws; ws += TT;
    float* i0  = ws; ws += TT;
    float* g1  = ws; ws += TT;
    float* i1  = ws; ws += TT;

    dim3 grid(TT / ROWS), block(256);
    k1_kernel<<<grid, block, 0, stream>>>(
        emb, start, w_in, b_in,
        w_v, b_v, w_q, b_q, w_k, b_k, w_o, b_o, w_f, b_f, w_i, b_i,
        e, k0b, v0b, q0b, o0b, g0, i0);
    k2_kernel<<<grid, block, 0, stream>>>(
        start, e, k0b, v0b, q0b, o0b, g0, i0,
        w_ff, b_ff,
        w_v + HH * HH, b_v + HH, w_q + HH * HH, b_q + HH,
        w_k + HH * HH, b_k + HH, w_o + HH * HH, b_o + HH,
        w_f + HH, b_f + 1, w_i + HH, b_i + 1,
        k1b, v1b, q1b, o1b, g1, i1);
    k3_kernel<<<grid, block, 0, stream>>>(
        start, e, k1b, v1b, q1b, o1b, g1, i1,
        w_ff + HH * 2 * HH, b_ff + HH, w_out, b_out, out);
}

// Round 4
// 165.302 us; speedup vs baseline: 1.4940x; 1.4940x over previous
//
#include <hip/hip_runtime.h>
#include <math.h>

#define TT 2048
#define HH 128
#define ROWS 8
#define SP 132  // LDS row stride in floats

__device__ __forceinline__ float dot4(float4 a, float4 b) {
    return a.x * b.x + a.y * b.y + a.z * b.z + a.w * b.w;
}

// ---- attention: wave wv owns row t0+wv (8 waves, 8 rows). lane covers dims {2l,2l+1}.
__device__ __forceinline__ void attn_row(int t0,
        const float* __restrict__ kb, const float* __restrict__ vb,
        const float* __restrict__ qb, const float* __restrict__ ob,
        const float* __restrict__ g, const float* __restrict__ iexp,
        const int* __restrict__ start, float* __restrict__ hs) {
    int tid = threadIdx.x;
    int wv = tid >> 6, lane = tid & 63;
    int t = t0 + wv;
    float2 q2 = *(const float2*)(qb + t * HH + 2 * lane);
    float nx = 0.f, ny = 0.f, dsum = 0.f, decay = 1.f;
    int tp = t;
    while (true) {
        float2 k2 = *(const float2*)(kb + tp * HH + 2 * lane);
        float p = k2.x * q2.x + k2.y * q2.y;
#pragma unroll
        for (int off = 1; off <= 32; off <<= 1) p += __shfl_xor(p, off, 64);
        float coeff = decay * iexp[tp] * p;
        float2 v2 = *(const float2*)(vb + tp * HH + 2 * lane);
        nx += coeff * v2.x; ny += coeff * v2.y;
        dsum += coeff;
        if (tp == 0 || start[tp]) break;
        decay *= g[tp];
        tp--;
    }
    float inv = 1.f / fmaxf(fabsf(dsum), 1.f);
    float2 o2 = *(const float2*)(ob + t * HH + 2 * lane);
    float2 h2;
    h2.x = o2.x * nx * inv;
    h2.y = o2.y * ny * inv;
    *(float2*)(hs + wv * SP + 2 * lane) = h2;
}

// ---- f/i scalar gates: wave wv handles row wv.
__device__ __forceinline__ void proj_fi(int t0, const float* __restrict__ xls,
        const float* __restrict__ w_f, const float* __restrict__ b_f,
        const float* __restrict__ w_i, const float* __restrict__ b_i,
        const int* __restrict__ start, float* __restrict__ g, float* __restrict__ iexp) {
    int tid = threadIdx.x;
    int wv = tid >> 6, lane = tid & 63;
    const float* x = xls + wv * SP + 2 * lane;
    float pf = x[0] * w_f[2 * lane] + x[1] * w_f[2 * lane + 1];
    float pi = x[0] * w_i[2 * lane] + x[1] * w_i[2 * lane + 1];
#pragma unroll
    for (int off = 1; off <= 32; off <<= 1) {
        pf += __shfl_xor(pf, off, 64);
        pi += __shfl_xor(pi, off, 64);
    }
    if (lane == 0) {
        int t = t0 + wv;
        g[t] = start[t] ? 0.f : 1.f / (1.f + expf(-(pf + b_f[0])));
        iexp[t] = expf(pi + b_i[0]);
    }
}

// ---- all-4 projection matrices in one c-loop. thread = (row=tid&7, hg=tid>>3, h0=2hg).
__device__ __forceinline__ void proj_block(int t0, const float* __restrict__ xls,
        const float* __restrict__ w_v, const float* __restrict__ b_v,
        const float* __restrict__ w_q, const float* __restrict__ b_q,
        const float* __restrict__ w_k, const float* __restrict__ b_k,
        const float* __restrict__ w_o, const float* __restrict__ b_o,
        float* __restrict__ vb, float* __restrict__ qb,
        float* __restrict__ kb, float* __restrict__ ob) {
    int tid = threadIdx.x;
    int row = tid & 7, hg = tid >> 3, h0 = 2 * hg;
    const float* xr = xls + row * SP;
    const float* wv0 = w_v + h0 * HH; const float* wv1 = wv0 + HH;
    const float* wq0 = w_q + h0 * HH; const float* wq1 = wq0 + HH;
    const float* wk0 = w_k + h0 * HH; const float* wk1 = wk0 + HH;
    const float* wo0 = w_o + h0 * HH; const float* wo1 = wo0 + HH;
    float2 av = {0, 0}, aq = {0, 0}, ak = {0, 0}, ao = {0, 0};
#pragma unroll 4
    for (int c = 0; c < HH; c += 4) {
        float4 x4 = *(const float4*)(xr + c);
        av.x += dot4(x4, *(const float4*)(wv0 + c));
        av.y += dot4(x4, *(const float4*)(wv1 + c));
        aq.x += dot4(x4, *(const float4*)(wq0 + c));
        aq.y += dot4(x4, *(const float4*)(wq1 + c));
        ak.x += dot4(x4, *(const float4*)(wk0 + c));
        ak.y += dot4(x4, *(const float4*)(wk1 + c));
        ao.x += dot4(x4, *(const float4*)(wo0 + c));
        ao.y += dot4(x4, *(const float4*)(wo1 + c));
    }
    const float ks = 0.088388347648318447f;  // 1/sqrt(128)
    int t = t0 + row;
    float2 bv = *(const float2*)(b_v + h0);
    float2 bq = *(const float2*)(b_q + h0);
    float2 bk = *(const float2*)(b_k + h0);
    float2 bo = *(const float2*)(b_o + h0);
    float2 rv = {av.x + bv.x, av.y + bv.y};
    float2 rq = {aq.x + bq.x, aq.y + bq.y};
    float2 rk = {ak.x * ks + bk.x, ak.y * ks + bk.y};
    float2 ro = {1.f / (1.f + expf(-(ao.x + bo.x))), 1.f / (1.f + expf(-(ao.y + bo.y)))};
    *(float2*)(vb + t * HH + h0) = rv;
    *(float2*)(qb + t * HH + h0) = rq;
    *(float2*)(kb + t * HH + h0) = rk;
    *(float2*)(ob + t * HH + h0) = ro;
}

// ---- ff: z = lrelu([h, e] @ w_ff.T + b_ff); writes zs LDS.
__device__ __forceinline__ void ff_block(const float* __restrict__ hsb,
        const float* __restrict__ esb, const float* __restrict__ w_ff,
        const float* __restrict__ b_ff, float* __restrict__ zs) {
    int tid = threadIdx.x;
    int row = tid & 7, hg = tid >> 3, h0 = 2 * hg;
    const float* w0 = w_ff + h0 * 256;
    const float* w1 = w0 + 256;
    const float* hr = hsb + row * SP;
    const float* er = esb + row * SP;
    float2 aff = {0, 0};
#pragma unroll 8
    for (int c = 0; c < 128; c += 4) {
        float4 xh = *(const float4*)(hr + c);
        float4 xe = *(const float4*)(er + c);
        aff.x += dot4(xh, *(const float4*)(w0 + c));
        aff.y += dot4(xh, *(const float4*)(w1 + c));
        aff.x += dot4(xe, *(const float4*)(w0 + 128 + c));
        aff.y += dot4(xe, *(const float4*)(w1 + 128 + c));
    }
    float2 bf = *(const float2*)(b_ff + h0);
    float2 z2;
    z2.x = aff.x + bf.x; z2.y = aff.y + bf.y;
    z2.x = z2.x > 0.f ? z2.x : 0.01f * z2.x;
    z2.y = z2.y > 0.f ? z2.y : 0.01f * z2.y;
    *(float2*)(zs + row * SP + h0) = z2;
}

// ---------------- K1: e = emb @ w_in.T + b_in; layer-0 projections ----------------
__global__ __launch_bounds__(512, 2) void k1_kernel(
        const float* __restrict__ emb, const int* __restrict__ start,
        const float* __restrict__ w_in, const float* __restrict__ b_in,
        const float* __restrict__ w_v, const float* __restrict__ b_v,
        const float* __restrict__ w_q, const float* __restrict__ b_q,
        const float* __restrict__ w_k, const float* __restrict__ b_k,
        const float* __restrict__ w_o, const float* __restrict__ b_o,
        const float* __restrict__ w_f, const float* __restrict__ b_f,
        const float* __restrict__ w_i, const float* __restrict__ b_i,
        float* __restrict__ e, float* __restrict__ kb, float* __restrict__ vb,
        float* __restrict__ qb, float* __restrict__ ob,
        float* __restrict__ g, float* __restrict__ iexp) {
    __shared__ float xs[ROWS * SP];
    __shared__ float es[ROWS * SP];
    int tid = threadIdx.x;
    int t0 = blockIdx.x * ROWS;
    int wv = tid >> 6, lane = tid & 63;
    *(float2*)(xs + wv * SP + 2 * lane) = *(const float2*)(emb + (t0 + wv) * HH + 2 * lane);
    __syncthreads();
    int row = tid & 7, hg = tid >> 3, h0 = 2 * hg;
    const float* xr = xs + row * SP;
    const float* w0 = w_in + h0 * HH;
    const float* w1 = w0 + HH;
    float2 a = {0, 0};
#pragma unroll 8
    for (int c = 0; c < HH; c += 4) {
        float4 x4 = *(const float4*)(xr + c);
        a.x += dot4(x4, *(const float4*)(w0 + c));
        a.y += dot4(x4, *(const float4*)(w1 + c));
    }
    float2 bi2 = *(const float2*)(b_in + h0);
    a.x += bi2.x; a.y += bi2.y;
    int t = t0 + row;
    *(float2*)(e + t * HH + h0) = a;
    *(float2*)(es + row * SP + h0) = a;
    __syncthreads();
    proj_block(t0, es, w_v, b_v, w_q, b_q, w_k, b_k, w_o, b_o, vb, qb, kb, ob);
    proj_fi(t0, es, w_f, b_f, w_i, b_i, start, g, iexp);
}

// ---------------- K2: attn0 + ff0 + layer-1 projections ----------------
__global__ __launch_bounds__(512, 2) void k2_kernel(
        const int* __restrict__ start, const float* __restrict__ e,
        const float* __restrict__ k0, const float* __restrict__ v0,
        const float* __restrict__ q0, const float* __restrict__ o0,
        const float* __restrict__ g0, const float* __restrict__ i0,
        const float* __restrict__ w_ff, const float* __restrict__ b_ff,
        const float* __restrict__ w_v, const float* __restrict__ b_v,
        const float* __restrict__ w_q, const float* __restrict__ b_q,
        const float* __restrict__ w_k, const float* __restrict__ b_k,
        const float* __restrict__ w_o, const float* __restrict__ b_o,
        const float* __restrict__ w_f, const float* __restrict__ b_f,
        const float* __restrict__ w_i, const float* __restrict__ b_i,
        float* __restrict__ kb, float* __restrict__ vb,
        float* __restrict__ qb, float* __restrict__ ob,
        float* __restrict__ g, float* __restrict__ iexp) {
    __shared__ float es[ROWS * SP];
    __shared__ float hs[ROWS * SP];
    __shared__ float zs[ROWS * SP];
    int tid = threadIdx.x;
    int t0 = blockIdx.x * ROWS;
    int wv = tid >> 6, lane = tid & 63;
    float2 ev = *(const float2*)(e + (t0 + wv) * HH + 2 * lane);
    attn_row(t0, k0, v0, q0, o0, g0, i0, start, hs);
    *(float2*)(es + wv * SP + 2 * lane) = ev;
    __syncthreads();
    ff_block(hs, es, w_ff, b_ff, zs);
    __syncthreads();
    proj_block(t0, zs, w_v, b_v, w_q, b_q, w_k, b_k, w_o, b_o, vb, qb, kb, ob);
    proj_fi(t0, zs, w_f, b_f, w_i, b_i, start, g, iexp);
}

// ---------------- K3: attn1 + ff1 + final dense ----------------
__global__ __launch_bounds__(512, 2) void k3_kernel(
        const int* __restrict__ start, const float* __restrict__ e,
        const float* __restrict__ k1, const float* __restrict__ v1,
        const float* __restrict__ q1, const float* __restrict__ o1,
        const float* __restrict__ g1, const float* __restrict__ i1,
        const float* __restrict__ w_ff, const float* __restrict__ b_ff,
        const float* __restrict__ w_out, const float* __restrict__ b_out,
        float* __restrict__ out) {
    __shared__ float es[ROWS * SP];
    __shared__ float hs[ROWS * SP];
    __shared__ float zs[ROWS * SP];
    int tid = threadIdx.x;
    int t0 = blockIdx.x * ROWS;
    int wv = tid >> 6, lane = tid & 63;
    float2 ev = *(const float2*)(e + (t0 + wv) * HH + 2 * lane);
    attn_row(t0, k1, v1, q1, o1, g1, i1, start, hs);
    *(float2*)(es + wv * SP + 2 * lane) = ev;
    __syncthreads();
    ff_block(hs, es, w_ff, b_ff, zs);
    __syncthreads();
    int row = tid & 7, hg = tid >> 3, h0 = 2 * hg;
    const float* zr = zs + row * SP;
    const float* w0 = w_out + h0 * HH;
    const float* w1 = w0 + HH;
    float2 a = {0, 0};
#pragma unroll 8
    for (int c = 0; c < HH; c += 4) {
        float4 z4 = *(const float4*)(zr + c);
        a.x += dot4(z4, *(const float4*)(w0 + c));
        a.y += dot4(z4, *(const float4*)(w1 + c));
    }
    float2 bo2 = *(const float2*)(b_out + h0);
    a.x += bo2.x; a.y += bo2.y;
    int t = t0 + row;
    *(float2*)(out + t * HH + h0) = a;
}

extern "C" void kernel_launch(void* const* d_in, const int* in_sizes, int n_in,
                              void* d_out, int out_size, void* d_ws, size_t ws_size,
                              hipStream_t stream) {
    const float* emb   = (const float*)d_in[0];
    const int*   start = (const int*)  d_in[1];
    const float* w_in  = (const float*)d_in[2];
    const float* b_in  = (const float*)d_in[3];
    const float* w_out = (const float*)d_in[4];
    const float* b_out = (const float*)d_in[5];
    const float* w_f   = (const float*)d_in[6];
    const float* b_f   = (const float*)d_in[7];
    const float* w_i   = (const float*)d_in[8];
    const float* b_i   = (const float*)d_in[9];
    const float* w_v   = (const float*)d_in[10];
    const float* b_v   = (const float*)d_in[11];
    const float* w_q   = (const float*)d_in[12];
    const float* b_q   = (const float*)d_in[13];
    const float* w_k   = (const float*)d_in[14];
    const float* b_k   = (const float*)d_in[15];
    const float* w_o   = (const float*)d_in[16];
    const float* b_o   = (const float*)d_in[17];
    const float* w_ff  = (const float*)d_in[18];
    const float* b_ff  = (const float*)d_in[19];
    float* out = (float*)d_out;

    float* ws = (float*)d_ws;
    float* e   = ws; ws += TT * HH;
    float* k0b = ws; ws += TT * HH;
    float* v0b = ws; ws += TT * HH;
    float* q0b = ws; ws += TT * HH;
    float* o0b = ws; ws += TT * HH;
    float* k1b = ws; ws += TT * HH;
    float* v1b = ws; ws += TT * HH;
    float* q1b = ws; ws += TT * HH;
    float* o1b = ws; ws += TT * HH;
    float* g0  = ws; ws += TT;
    float* i0  = ws; ws += TT;
    float* g1  = ws; ws += TT;
    float* i1  = ws; ws += TT;

    dim3 grid(TT / ROWS), block(512);
    k1_kernel<<<grid, block, 0, stream>>>(
        emb, start, w_in, b_in,
        w_v, b_v, w_q, b_q, w_k, b_k, w_o, b_o, w_f, b_f, w_i, b_i,
        e, k0b, v0b, q0b, o0b, g0, i0);
    k2_kernel<<<grid, block, 0, stream>>>(
        start, e, k0b, v0b, q0b, o0b, g0, i0,
        w_ff, b_ff,
        w_v + HH * HH, b_v + HH, w_q + HH * HH, b_q + HH,
        w_k + HH * HH, b_k + HH, w_o + HH * HH, b_o + HH,
        w_f + HH, b_f + 1, w_i + HH, b_i + 1,
        k1b, v1b, q1b, o1b, g1, i1);
    k3_kernel<<<grid, block, 0, stream>>>(
        start, e, k1b, v1b, q1b, o1b, g1, i1,
        w_ff + HH * 2 * HH, b_ff + HH, w_out, b_out, out);
}